// Round 2
// baseline (406.839 us; speedup 1.0000x reference)
//
#include <hip/hip_runtime.h>

typedef unsigned short ushort;
typedef unsigned int uint;
typedef __attribute__((ext_vector_type(8))) short short8;
typedef __attribute__((ext_vector_type(4))) float float4v;

#define D_MODEL 1024
#define NH 16
#define DH 64
#define BATCH 2
#define SEQ 1024
#define MEMLEN 1024
#define TOT 2048

__device__ __forceinline__ float b2f(ushort u) {
  return __uint_as_float(((uint)u) << 16);
}
__device__ __forceinline__ ushort f2b(float f) {
  uint i = __float_as_uint(f);
  uint r = (i + 0x7fffu + ((i >> 16) & 1u)) >> 16;
  return (ushort)r;
}
__device__ __forceinline__ void gld16(const ushort* g, ushort* l) {
  __builtin_amdgcn_global_load_lds(
      (const __attribute__((address_space(1))) void*)g,
      (__attribute__((address_space(3))) void*)l, 16, 0, 0);
}

// ------------------------------------------------- concat + cast to bf16 ----
__global__ __launch_bounds__(256) void concat_cvt_kernel(
    const float* __restrict__ x, const float* __restrict__ mem,
    ushort* __restrict__ xt, ushort* __restrict__ xb) {
  int idx = blockIdx.x * 256 + threadIdx.x;
  int row = idx >> 7;
  int c8 = (idx & 127) << 3;
  int b = row >> 11;
  int i = row & 2047;
  const float* src = (i < MEMLEN) ? &mem[((b << 10) + i) * D_MODEL]
                                  : &x[((b << 10) + (i - MEMLEN)) * D_MODEL];
  float4 f0 = *(const float4*)(&src[c8]);
  float4 f1 = *(const float4*)(&src[c8 + 4]);
  ushort u[8] = {f2b(f0.x), f2b(f0.y), f2b(f0.z), f2b(f0.w),
                 f2b(f1.x), f2b(f1.y), f2b(f1.z), f2b(f1.w)};
  *(uint4*)(&xt[row * D_MODEL + c8]) = *(const uint4*)u;
  if (i >= MEMLEN)
    *(uint4*)(&xb[((b << 10) + (i - MEMLEN)) * D_MODEL + c8]) = *(const uint4*)u;
}

// --------------------------------------------------- fp32 -> bf16 cast ------
__global__ __launch_bounds__(256) void cvt_kernel(const float* __restrict__ in,
                                                  ushort* __restrict__ out) {
  int idx = blockIdx.x * 256 + threadIdx.x;
  int base = idx << 3;
  float4 f0 = *(const float4*)(&in[base]);
  float4 f1 = *(const float4*)(&in[base + 4]);
  ushort u[8] = {f2b(f0.x), f2b(f0.y), f2b(f0.z), f2b(f0.w),
                 f2b(f1.x), f2b(f1.y), f2b(f1.z), f2b(f1.w)};
  *(uint4*)(&out[base]) = *(const uint4*)u;
}

// --------------------- mask -> bf16 pre-multiplied by -1e9 ------------------
__global__ __launch_bounds__(256) void maskcvt_kernel(
    const float* __restrict__ in, ushort* __restrict__ out) {
  int idx = blockIdx.x * 256 + threadIdx.x;
  int base = idx << 3;
  float4 f0 = *(const float4*)(&in[base]);
  float4 f1 = *(const float4*)(&in[base + 4]);
  ushort u[8] = {f2b(f0.x * -1e9f), f2b(f0.y * -1e9f), f2b(f0.z * -1e9f),
                 f2b(f0.w * -1e9f), f2b(f1.x * -1e9f), f2b(f1.y * -1e9f),
                 f2b(f1.z * -1e9f), f2b(f1.w * -1e9f)};
  *(uint4*)(&out[base]) = *(const uint4*)u;
}

// --------------------------- 5x transpose + cast to bf16 (one launch) -------
__global__ __launch_bounds__(256) void transpose_cvt5_kernel(
    const float* __restrict__ W0, const float* __restrict__ W1,
    const float* __restrict__ W2, const float* __restrict__ W3,
    const float* __restrict__ W4, ushort* __restrict__ T0,
    ushort* __restrict__ T1, ushort* __restrict__ T2, ushort* __restrict__ T3,
    ushort* __restrict__ T4) {
  __shared__ ushort tle[32][33];
  const float* W;
  ushort* T;
  switch (blockIdx.z) {
    case 0: W = W0; T = T0; break;
    case 1: W = W1; T = T1; break;
    case 2: W = W2; T = T2; break;
    case 3: W = W3; T = T3; break;
    default: W = W4; T = T4; break;
  }
  const int bx = blockIdx.x * 32, by = blockIdx.y * 32;
  const int tx = threadIdx.x & 31, ty = threadIdx.x >> 5;
#pragma unroll
  for (int j = 0; j < 32; j += 8)
    tle[ty + j][tx] = f2b(W[(by + ty + j) * 1024 + bx + tx]);
  __syncthreads();
#pragma unroll
  for (int j = 0; j < 32; j += 8)
    T[(bx + ty + j) * 1024 + by + tx] = tle[tx][ty + j];
}

// ------------------------------------- V transpose: kv cols -> vt[b][d][t] --
__global__ __launch_bounds__(256) void vtrans_kernel(
    const ushort* __restrict__ kv, ushort* __restrict__ vt) {
  __shared__ ushort tle[32][76];
  const int gx = blockIdx.x;   // 32-row (b,t) tiles
  const int gy = blockIdx.y;   // 64-wide d tiles
  const int tid = threadIdx.x;
  const int r = tid >> 3, c8 = (tid & 7) * 8;
  *(uint4*)(&tle[r][c8]) =
      *(const uint4*)(&kv[(gx * 32 + r) * 2048 + 1024 + gy * 64 + c8]);
  __syncthreads();
  const int dr = tid >> 2, tc8 = (tid & 3) * 8;
  const int bb = (gx * 32) >> 11, tbase = (gx * 32) & 2047;
  ushort tmp[8];
#pragma unroll
  for (int j = 0; j < 8; ++j) tmp[j] = tle[tc8 + j][dr];
  *(uint4*)(&vt[((bb << 10) + gy * 64 + dr) * 2048 + tbase + tc8]) =
      *(const uint4*)tmp;
}

// -------------------------------------------------- 128x128 m97-style GEMM --
// KV projection: cols<1024 = K (scaled 0.125 with bke), cols>=1024 = V (bv).
__global__ __launch_bounds__(256) void gemm128_kernel(
    const ushort* __restrict__ A, const ushort* __restrict__ BT,
    const float* __restrict__ b0, const float* __restrict__ b1,
    ushort* __restrict__ Cout, int M, int N, int K) {
  __shared__ ushort As[128 * 32];
  __shared__ ushort Bs[128 * 32];
  const int m0 = blockIdx.x * 128, n0 = blockIdx.y * 128;
  const int tid = threadIdx.x;
  const int w = tid >> 6, lane = tid & 63, m15 = lane & 15, q4 = lane >> 4;
  const int wm = w & 1, wn = w >> 1;
  float4v acc[4][4] = {};
  const int c0 = tid, c1 = tid + 256;
  const int r0 = c0 >> 2, u0 = (c0 & 3) * 8;
  const int r1 = c1 >> 2, u1 = (c1 & 3) * 8;

  for (int kk = 0; kk < K; kk += 32) {
    __syncthreads();
    gld16(&A[(m0 + r0) * K + kk + u0], &As[c0 * 8]);
    gld16(&A[(m0 + r1) * K + kk + u1], &As[c1 * 8]);
    gld16(&BT[(n0 + r0) * K + kk + u0], &Bs[c0 * 8]);
    gld16(&BT[(n0 + r1) * K + kk + u1], &Bs[c1 * 8]);
    __syncthreads();
    short8 af[4], bf[4];
#pragma unroll
    for (int i = 0; i < 4; ++i)
      af[i] = *(const short8*)(&As[(wm * 64 + i * 16 + m15) * 32 + q4 * 8]);
#pragma unroll
    for (int j = 0; j < 4; ++j)
      bf[j] = *(const short8*)(&Bs[(wn * 64 + j * 16 + m15) * 32 + q4 * 8]);
#pragma unroll
    for (int i = 0; i < 4; ++i)
#pragma unroll
      for (int j = 0; j < 4; ++j)
        acc[i][j] =
            __builtin_amdgcn_mfma_f32_16x16x32_bf16(af[i], bf[j], acc[i][j], 0, 0, 0);
  }
#pragma unroll
  for (int j = 0; j < 4; ++j) {
    int col = n0 + wn * 64 + j * 16 + m15;
    float bv = (col < 1024) ? b0[col] : b1[col - 1024];
    float sc = (col < 1024) ? 0.125f : 1.0f;   // pre-scale K by 1/8 (exact)
#pragma unroll
    for (int i = 0; i < 4; ++i) {
      int rowb = m0 + wm * 64 + i * 16 + q4 * 4;
#pragma unroll
      for (int r = 0; r < 4; ++r)
        Cout[(rowb + r) * N + col] = f2b((acc[i][j][r] + bv) * sc);
    }
  }
}

// -------------------------------------- 64x128-tile GEMM (for small M) ------
template <int EPI>
__global__ __launch_bounds__(256) void gemm64_kernel(
    const ushort* __restrict__ A, const ushort* __restrict__ BT0,
    const ushort* __restrict__ BT1, int rowSplit, const float* __restrict__ b0,
    const float* __restrict__ b1, void* __restrict__ Cout, int M, int N, int K) {
  __shared__ ushort As[64 * 32];
  __shared__ ushort Bs[128 * 32];
  const int m0 = blockIdx.x * 64, n0 = blockIdx.y * 128;
  const ushort* BT = (m0 < rowSplit) ? BT0 : BT1;
  const float* bias = (m0 < rowSplit) ? b0 : b1;
  const int tid = threadIdx.x;
  const int w = tid >> 6, lane = tid & 63, m15 = lane & 15, q4 = lane >> 4;
  float4v acc[4][2] = {};
  const int ra = tid >> 2, ua = (tid & 3) * 8;
  const int c0 = tid, c1 = tid + 256;
  const int rb0 = c0 >> 2, ub0 = (c0 & 3) * 8;
  const int rb1 = c1 >> 2, ub1 = (c1 & 3) * 8;

  for (int kk = 0; kk < K; kk += 32) {
    __syncthreads();
    gld16(&A[(m0 + ra) * K + kk + ua], &As[tid * 8]);
    gld16(&BT[(n0 + rb0) * K + kk + ub0], &Bs[c0 * 8]);
    gld16(&BT[(n0 + rb1) * K + kk + ub1], &Bs[c1 * 8]);
    __syncthreads();
    short8 bf[2];
#pragma unroll
    for (int j = 0; j < 2; ++j)
      bf[j] = *(const short8*)(&Bs[(w * 32 + j * 16 + m15) * 32 + q4 * 8]);
#pragma unroll
    for (int i = 0; i < 4; ++i) {
      short8 af = *(const short8*)(&As[(i * 16 + m15) * 32 + q4 * 8]);
#pragma unroll
      for (int j = 0; j < 2; ++j)
        acc[i][j] =
            __builtin_amdgcn_mfma_f32_16x16x32_bf16(af, bf[j], acc[i][j], 0, 0, 0);
    }
  }
#pragma unroll
  for (int j = 0; j < 2; ++j) {
    int col = n0 + w * 32 + j * 16 + m15;
    float bv = bias[col];
#pragma unroll
    for (int i = 0; i < 4; ++i) {
      int rowb = m0 + i * 16 + q4 * 4;
#pragma unroll
      for (int r = 0; r < 4; ++r) {
        float v = acc[i][j][r] + bv;
        if (EPI == 1)
          ((float*)Cout)[(rowb + r) * N + col] = v;
        else
          ((ushort*)Cout)[(rowb + r) * N + col] = f2b(v);
      }
    }
  }
}

// ------------- Bhat batched GEMM, scatter-shifted output + mask fold --------
// Computes Bhat[s_p, u] = 0.125 * q[s_p].Qrel[u] and writes it directly to the
// SHIFTED layout consumed by attention:
//   consumer (s,t) reads Bhat[s, t-s+1023]        (u+s_p >= 1023 branch)
//   or        (s,t) reads Bhat[s+1, t-s-1026]     (wrap branch, row s_p-1)
// Exactly one destination per element; (s_p==0, low-u) elements are dropped.
// Mask (pre-scaled by -1e9 in maskb) is folded in so attn reads one stream.
__global__ __launch_bounds__(256) void bhat_kernel(
    const ushort* __restrict__ q, const ushort* __restrict__ Qrb,
    const ushort* __restrict__ maskb, ushort* __restrict__ Bsh) {
  __shared__ ushort As[2 * 128 * 32];
  __shared__ ushort Bs[2 * 128 * 32];
  const int bs0 = blockIdx.x * 128, u0 = blockIdx.y * 128, h = blockIdx.z;
  const int tid = threadIdx.x;
  const int w = tid >> 6, lane = tid & 63, m15 = lane & 15, q4 = lane >> 4;
  const int wm = w & 1, wn = w >> 1;

#pragma unroll
  for (int c = 0; c < 4; ++c) {
    int unit = c * 256 + tid;               // flat LDS ushort = unit*8
    int row = (unit >> 2) & 127, kh = unit >> 9, cu = unit & 3;
    gld16(&q[(bs0 + row) * 1024 + (h << 6) + kh * 32 + cu * 8], &As[unit * 8]);
    gld16(&Qrb[(u0 + row) * 1024 + (h << 6) + kh * 32 + cu * 8], &Bs[unit * 8]);
  }
  __syncthreads();

  float4v acc[4][4] = {};
#pragma unroll
  for (int kh = 0; kh < 2; ++kh) {
    short8 af[4], bf[4];
#pragma unroll
    for (int i = 0; i < 4; ++i)
      af[i] = *(const short8*)(&As[kh * 4096 + (wm * 64 + i * 16 + m15) * 32 + q4 * 8]);
#pragma unroll
    for (int j = 0; j < 4; ++j)
      bf[j] = *(const short8*)(&Bs[kh * 4096 + (wn * 64 + j * 16 + m15) * 32 + q4 * 8]);
#pragma unroll
    for (int i = 0; i < 4; ++i)
#pragma unroll
      for (int j = 0; j < 4; ++j)
        acc[i][j] =
            __builtin_amdgcn_mfma_f32_16x16x32_bf16(af[i], bf[j], acc[i][j], 0, 0, 0);
  }
  const int b = bs0 >> 10;
  const int s0loc = bs0 & 1023;
  const size_t plane = (size_t)((b << 4) + h) * (size_t)(1024 * 2048);
#pragma unroll
  for (int j = 0; j < 4; ++j) {
    int u = u0 + wn * 64 + j * 16 + m15;
#pragma unroll
    for (int i = 0; i < 4; ++i) {
      int sp0 = s0loc + wm * 64 + i * 16 + q4 * 4;
#pragma unroll
      for (int r = 0; r < 4; ++r) {
        int sp = sp0 + r;
        int sel = (u + sp >= 1023) ? 1 : 0;
        int row = sp - 1 + sel;
        int t = u + sp - 1023 + (sel ? 0 : 2048);
        if (row >= 0) {
          float mval = b2f(maskb[row * 2048 + t]);
          Bsh[plane + (size_t)row * 2048 + t] =
              f2b(acc[i][j][r] * 0.125f + mval);
        }
      }
    }
  }
}

// ------- fill the shift-trick zero diagonal: Bsh[s][s+1025] = mask only -----
__global__ __launch_bounds__(256) void zdiag_kernel(
    const ushort* __restrict__ maskb, ushort* __restrict__ Bsh) {
  int idx = blockIdx.x * 256 + threadIdx.x;   // 32 planes x 1024 s
  int plane = idx >> 10, s = idx & 1023;
  if (s >= 1023) return;
  int t = s + 1025;
  Bsh[(size_t)plane * (size_t)(1024 * 2048) + s * 2048 + t] = maskb[s * 2048 + t];
}

// ----------------- fused attention: QK + shifted-B read + exp + PV ----------
// Wave-independent: wave = (st s-tile 16 rows, th T-half). Chunks of 32 t.
// ZERO barriers in the loop. Register double-buffer: chunk n+1's K/V/B loads
// are issued before chunk n's compute (compiler emits counted vmcnt).
// Bsh is pre-shifted + mask-folded: score = A + b2f(Bsh[s][t]).
__global__ __launch_bounds__(256) void attn_kernel(
    const ushort* __restrict__ qb, const ushort* __restrict__ kv,
    const ushort* __restrict__ vt, const ushort* __restrict__ Bsh,
    ushort* __restrict__ attn) {
  __shared__ ushort Pp[4][16 * 36];
  __shared__ float comb[2][16][68];
  __shared__ float csum[32];

  const int tid = threadIdx.x;
  const int w = tid >> 6, lane = tid & 63, m15 = lane & 15, q4 = lane >> 4;
  const int st = w & 1, th = w >> 1;
  const int s0w = blockIdx.x * 32 + st * 16;
  const int h = blockIdx.y, b = blockIdx.z;
  const int s_l = q4 * 4;

  const ushort* qp = &qb[((b << 10) + s0w + m15) * 1024 + (h << 6) + q4 * 8];
  const short8 af0 = *(const short8*)qp;
  const short8 af1 = *(const short8*)(qp + 32);

  const ushort* kvb = &kv[((size_t)(b << 11) * 2048) + (h << 6)];
  const ushort* vtb = &vt[((size_t)((b << 10) + (h << 6))) * 2048];
  const ushort* bshb = &Bsh[(size_t)((b << 4) + h) * (size_t)(1024 * 2048) +
                            (size_t)(s0w + s_l) * 2048];
  ushort* pw = &Pp[w][0];

  float lsum4[4] = {0.f, 0.f, 0.f, 0.f};
  float4v oacc[4] = {};

  short8 K0[2][2], V0[4];
  short8 K1[2][2], V1[4];
  ushort B0[8], B1[8];

  auto loadc = [&](int t0, short8 (&K)[2][2], short8 (&V)[4], ushort (&B)[8]) {
#pragma unroll
    for (int nt = 0; nt < 2; ++nt) {
      const ushort* kp = &kvb[(size_t)(t0 + nt * 16 + m15) * 2048 + q4 * 8];
      K[nt][0] = *(const short8*)kp;
      K[nt][1] = *(const short8*)(kp + 32);
    }
#pragma unroll
    for (int nd = 0; nd < 4; ++nd)
      V[nd] = *(const short8*)(&vtb[(size_t)(nd * 16 + m15) * 2048 + t0 + q4 * 8]);
#pragma unroll
    for (int nt = 0; nt < 2; ++nt)
#pragma unroll
      for (int i = 0; i < 4; ++i)
        B[nt * 4 + i] = bshb[i * 2048 + t0 + nt * 16 + m15];
  };

  auto computec = [&](short8 (&K)[2][2], short8 (&V)[4], ushort (&B)[8]) {
#pragma unroll
    for (int nt = 0; nt < 2; ++nt) {
      float4v a = {0.f, 0.f, 0.f, 0.f};
      a = __builtin_amdgcn_mfma_f32_16x16x32_bf16(af0, K[nt][0], a, 0, 0, 0);
      a = __builtin_amdgcn_mfma_f32_16x16x32_bf16(af1, K[nt][1], a, 0, 0, 0);
#pragma unroll
      for (int i = 0; i < 4; ++i) {
        float p = __expf(a[i] + b2f(B[nt * 4 + i]));
        lsum4[i] += p;
        pw[(s_l + i) * 36 + nt * 16 + m15] = f2b(p);
      }
    }
    short8 pfr = *(const short8*)(&pw[m15 * 36 + q4 * 8]);
#pragma unroll
    for (int nd = 0; nd < 4; ++nd)
      oacc[nd] = __builtin_amdgcn_mfma_f32_16x16x32_bf16(pfr, V[nd], oacc[nd], 0, 0, 0);
  };

  const int tb = th * 1024;
  loadc(tb, K0, V0, B0);
  for (int ci2 = 0; ci2 < 16; ++ci2) {
    const int t0 = tb + ci2 * 64;
    loadc(t0 + 32, K1, V1, B1);
    computec(K0, V0, B0);
    if (ci2 < 15) loadc(t0 + 64, K0, V0, B0);
    computec(K1, V1, B1);
  }

  // row sums across the 16 t-lanes (m15 butterfly)
#pragma unroll
  for (int i = 0; i < 4; ++i) {
    float v = lsum4[i];
    v += __shfl_xor(v, 1, 64);
    v += __shfl_xor(v, 2, 64);
    v += __shfl_xor(v, 4, 64);
    v += __shfl_xor(v, 8, 64);
    lsum4[i] = v;
  }
  // combine T-halves
  if (th == 1) {
#pragma unroll
    for (int nd = 0; nd < 4; ++nd)
#pragma unroll
      for (int i = 0; i < 4; ++i)
        comb[st][s_l + i][nd * 16 + m15] = oacc[nd][i];
    if (m15 == 0)
#pragma unroll
      for (int i = 0; i < 4; ++i) csum[st * 16 + s_l + i] = lsum4[i];
  }
  __syncthreads();
  if (th == 0) {
#pragma unroll
    for (int i = 0; i < 4; ++i) lsum4[i] += csum[st * 16 + s_l + i];
#pragma unroll
    for (int nd = 0; nd < 4; ++nd)
#pragma unroll
      for (int i = 0; i < 4; ++i) {
        float v = oacc[nd][i] + comb[st][s_l + i][nd * 16 + m15];
        attn[((b << 10) + s0w + s_l + i) * 1024 + (h << 6) + nd * 16 + m15] =
            f2b(v / lsum4[i]);
      }
  }
}

// ---------------------------------------------------------------- launch ----
extern "C" void kernel_launch(void* const* d_in, const int* in_sizes, int n_in,
                              void* d_out, int out_size, void* d_ws,
                              size_t ws_size, hipStream_t stream) {
  const float* x = (const float*)d_in[0];
  const float* mem = (const float*)d_in[1];
  const float* mask = (const float*)d_in[2];
  const float* rel = (const float*)d_in[3];
  const float* Wq = (const float*)d_in[4];
  const float* bq = (const float*)d_in[5];
  const float* Wke = (const float*)d_in[6];
  const float* bke = (const float*)d_in[7];
  const float* Wkr = (const float*)d_in[8];
  const float* bkr = (const float*)d_in[9];
  const float* Wv = (const float*)d_in[10];
  const float* bv = (const float*)d_in[11];
  const float* Wo = (const float*)d_in[12];
  const float* bo = (const float*)d_in[13];
  float* out = (float*)d_out;

  ushort* ws = (ushort*)d_ws;
  ushort* xt = ws;                          // 4096x1024 (reused as vt)
  ushort* xbrel = xt + 4096 * 1024;         // [xb(2048); relb(2048)] x 1024
  ushort* WqT = xbrel + 4096 * 1024;
  ushort* WkeT = WqT + 1024 * 1024;
  ushort* WvT = WkeT + 1024 * 1024;
  ushort* WkrT = WvT + 1024 * 1024;
  ushort* WoT = WkrT + 1024 * 1024;
  ushort* kv = WoT + 1024 * 1024;           // 4096x2048 (K cols 0..1023 scaled, V 1024..)
  ushort* qr = kv + 4096 * 2048;            // [qbuf(2048); Qrb(2048)] x 1024
  ushort* attn = qr + 4096 * 1024;          // 2048x1024
  ushort* maskb = attn + 2048 * 1024;       // 1024x2048 bf16 pre-scaled
  ushort* Bsh = maskb + 1024 * 2048;        // [b*16+h][1024 s][2048 t] bf16, SHIFTED
  ushort* relb = xbrel + 2048 * 1024;
  ushort* Qrb = qr + 2048 * 1024;
  ushort* vt = xt;

  concat_cvt_kernel<<<2048, 256, 0, stream>>>(x, mem, xt, xbrel);
  cvt_kernel<<<1024, 256, 0, stream>>>(rel, relb);
  maskcvt_kernel<<<1024, 256, 0, stream>>>(mask, maskb);
  transpose_cvt5_kernel<<<dim3(32, 32, 5), 256, 0, stream>>>(
      Wq, Wke, Wkr, Wv, Wo, WqT, WkeT, WkrT, WvT, WoT);

  gemm128_kernel<<<dim3(32, 16), 256, 0, stream>>>(xt, WkeT, bke, bv, kv,
                                                   4096, 2048, 1024);
  gemm64_kernel<0><<<dim3(64, 8), 256, 0, stream>>>(
      xbrel, WqT, WkrT, 2048, bq, bkr, qr, 4096, 1024, 1024);
  vtrans_kernel<<<dim3(128, 16), 256, 0, stream>>>(kv, vt);

  bhat_kernel<<<dim3(16, 16, 16), 256, 0, stream>>>(qr, Qrb, maskb, Bsh);
  zdiag_kernel<<<128, 256, 0, stream>>>(maskb, Bsh);

  attn_kernel<<<dim3(SEQ / 32, NH, BATCH), 256, 0, stream>>>(
      qr, kv, vt, Bsh, attn);

  gemm64_kernel<1><<<dim3(32, 8), 256, 0, stream>>>(
      attn, WoT, WoT, 1 << 30, bo, bo, out, 2048, 1024, 1024);
}

// Round 3
// 400.526 us; speedup vs baseline: 1.0158x; 1.0158x over previous
//
#include <hip/hip_runtime.h>

typedef unsigned short ushort;
typedef unsigned int uint;
typedef __attribute__((ext_vector_type(8))) short short8;
typedef __attribute__((ext_vector_type(4))) float float4v;

#define D_MODEL 1024
#define NH 16
#define DH 64
#define BATCH 2
#define SEQ 1024
#define MEMLEN 1024
#define TOT 2048

__device__ __forceinline__ float b2f(ushort u) {
  return __uint_as_float(((uint)u) << 16);
}
__device__ __forceinline__ ushort f2b(float f) {
  uint i = __float_as_uint(f);
  uint r = (i + 0x7fffu + ((i >> 16) & 1u)) >> 16;
  return (ushort)r;
}
__device__ __forceinline__ void gld16(const ushort* g, ushort* l) {
  __builtin_amdgcn_global_load_lds(
      (const __attribute__((address_space(1))) void*)g,
      (__attribute__((address_space(3))) void*)l, 16, 0, 0);
}

// ------------------------------------------------- concat + cast to bf16 ----
__global__ __launch_bounds__(256) void concat_cvt_kernel(
    const float* __restrict__ x, const float* __restrict__ mem,
    ushort* __restrict__ xt, ushort* __restrict__ xb) {
  int idx = blockIdx.x * 256 + threadIdx.x;
  int row = idx >> 7;
  int c8 = (idx & 127) << 3;
  int b = row >> 11;
  int i = row & 2047;
  const float* src = (i < MEMLEN) ? &mem[((b << 10) + i) * D_MODEL]
                                  : &x[((b << 10) + (i - MEMLEN)) * D_MODEL];
  float4 f0 = *(const float4*)(&src[c8]);
  float4 f1 = *(const float4*)(&src[c8 + 4]);
  ushort u[8] = {f2b(f0.x), f2b(f0.y), f2b(f0.z), f2b(f0.w),
                 f2b(f1.x), f2b(f1.y), f2b(f1.z), f2b(f1.w)};
  *(uint4*)(&xt[row * D_MODEL + c8]) = *(const uint4*)u;
  if (i >= MEMLEN)
    *(uint4*)(&xb[((b << 10) + (i - MEMLEN)) * D_MODEL + c8]) = *(const uint4*)u;
}

// --------------------------------------------------- fp32 -> bf16 cast ------
__global__ __launch_bounds__(256) void cvt_kernel(const float* __restrict__ in,
                                                  ushort* __restrict__ out) {
  int idx = blockIdx.x * 256 + threadIdx.x;
  int base = idx << 3;
  float4 f0 = *(const float4*)(&in[base]);
  float4 f1 = *(const float4*)(&in[base + 4]);
  ushort u[8] = {f2b(f0.x), f2b(f0.y), f2b(f0.z), f2b(f0.w),
                 f2b(f1.x), f2b(f1.y), f2b(f1.z), f2b(f1.w)};
  *(uint4*)(&out[base]) = *(const uint4*)u;
}

// --------------------- mask -> bf16 pre-multiplied by -1e9 ------------------
__global__ __launch_bounds__(256) void maskcvt_kernel(
    const float* __restrict__ in, ushort* __restrict__ out) {
  int idx = blockIdx.x * 256 + threadIdx.x;
  int base = idx << 3;
  float4 f0 = *(const float4*)(&in[base]);
  float4 f1 = *(const float4*)(&in[base + 4]);
  ushort u[8] = {f2b(f0.x * -1e9f), f2b(f0.y * -1e9f), f2b(f0.z * -1e9f),
                 f2b(f0.w * -1e9f), f2b(f1.x * -1e9f), f2b(f1.y * -1e9f),
                 f2b(f1.z * -1e9f), f2b(f1.w * -1e9f)};
  *(uint4*)(&out[base]) = *(const uint4*)u;
}

// --------------------------- 5x transpose + cast to bf16 (one launch) -------
__global__ __launch_bounds__(256) void transpose_cvt5_kernel(
    const float* __restrict__ W0, const float* __restrict__ W1,
    const float* __restrict__ W2, const float* __restrict__ W3,
    const float* __restrict__ W4, ushort* __restrict__ T0,
    ushort* __restrict__ T1, ushort* __restrict__ T2, ushort* __restrict__ T3,
    ushort* __restrict__ T4) {
  __shared__ ushort tle[32][33];
  const float* W;
  ushort* T;
  switch (blockIdx.z) {
    case 0: W = W0; T = T0; break;
    case 1: W = W1; T = T1; break;
    case 2: W = W2; T = T2; break;
    case 3: W = W3; T = T3; break;
    default: W = W4; T = T4; break;
  }
  const int bx = blockIdx.x * 32, by = blockIdx.y * 32;
  const int tx = threadIdx.x & 31, ty = threadIdx.x >> 5;
#pragma unroll
  for (int j = 0; j < 32; j += 8)
    tle[ty + j][tx] = f2b(W[(by + ty + j) * 1024 + bx + tx]);
  __syncthreads();
#pragma unroll
  for (int j = 0; j < 32; j += 8)
    T[(bx + ty + j) * 1024 + by + tx] = tle[tx][ty + j];
}

// ------------------------------------- V transpose: kv cols -> vt[b][d][t] --
__global__ __launch_bounds__(256) void vtrans_kernel(
    const ushort* __restrict__ kv, ushort* __restrict__ vt) {
  __shared__ ushort tle[32][76];
  const int gx = blockIdx.x;   // 32-row (b,t) tiles
  const int gy = blockIdx.y;   // 64-wide d tiles
  const int tid = threadIdx.x;
  const int r = tid >> 3, c8 = (tid & 7) * 8;
  *(uint4*)(&tle[r][c8]) =
      *(const uint4*)(&kv[(gx * 32 + r) * 2048 + 1024 + gy * 64 + c8]);
  __syncthreads();
  const int dr = tid >> 2, tc8 = (tid & 3) * 8;
  const int bb = (gx * 32) >> 11, tbase = (gx * 32) & 2047;
  ushort tmp[8];
#pragma unroll
  for (int j = 0; j < 8; ++j) tmp[j] = tle[tc8 + j][dr];
  *(uint4*)(&vt[((bb << 10) + gy * 64 + dr) * 2048 + tbase + tc8]) =
      *(const uint4*)tmp;
}

// -------------------------------------------------- 128x128 m97-style GEMM --
// KV projection: cols<1024 = K (scaled 0.125 with bke), cols>=1024 = V (bv).
__global__ __launch_bounds__(256) void gemm128_kernel(
    const ushort* __restrict__ A, const ushort* __restrict__ BT,
    const float* __restrict__ b0, const float* __restrict__ b1,
    ushort* __restrict__ Cout, int M, int N, int K) {
  __shared__ ushort As[128 * 32];
  __shared__ ushort Bs[128 * 32];
  const int m0 = blockIdx.x * 128, n0 = blockIdx.y * 128;
  const int tid = threadIdx.x;
  const int w = tid >> 6, lane = tid & 63, m15 = lane & 15, q4 = lane >> 4;
  const int wm = w & 1, wn = w >> 1;
  float4v acc[4][4] = {};
  const int c0 = tid, c1 = tid + 256;
  const int r0 = c0 >> 2, u0 = (c0 & 3) * 8;
  const int r1 = c1 >> 2, u1 = (c1 & 3) * 8;

  for (int kk = 0; kk < K; kk += 32) {
    __syncthreads();
    gld16(&A[(m0 + r0) * K + kk + u0], &As[c0 * 8]);
    gld16(&A[(m0 + r1) * K + kk + u1], &As[c1 * 8]);
    gld16(&BT[(n0 + r0) * K + kk + u0], &Bs[c0 * 8]);
    gld16(&BT[(n0 + r1) * K + kk + u1], &Bs[c1 * 8]);
    __syncthreads();
    short8 af[4], bf[4];
#pragma unroll
    for (int i = 0; i < 4; ++i)
      af[i] = *(const short8*)(&As[(wm * 64 + i * 16 + m15) * 32 + q4 * 8]);
#pragma unroll
    for (int j = 0; j < 4; ++j)
      bf[j] = *(const short8*)(&Bs[(wn * 64 + j * 16 + m15) * 32 + q4 * 8]);
#pragma unroll
    for (int i = 0; i < 4; ++i)
#pragma unroll
      for (int j = 0; j < 4; ++j)
        acc[i][j] =
            __builtin_amdgcn_mfma_f32_16x16x32_bf16(af[i], bf[j], acc[i][j], 0, 0, 0);
  }
#pragma unroll
  for (int j = 0; j < 4; ++j) {
    int col = n0 + wn * 64 + j * 16 + m15;
    float bv = (col < 1024) ? b0[col] : b1[col - 1024];
    float sc = (col < 1024) ? 0.125f : 1.0f;   // pre-scale K by 1/8 (exact)
#pragma unroll
    for (int i = 0; i < 4; ++i) {
      int rowb = m0 + wm * 64 + i * 16 + q4 * 4;
#pragma unroll
      for (int r = 0; r < 4; ++r)
        Cout[(rowb + r) * N + col] = f2b((acc[i][j][r] + bv) * sc);
    }
  }
}

// -------------------------------------- 64x128-tile GEMM (for small M) ------
// sc1 is applied to rows >= rowSplit (used to pre-scale Qrel by 1/8, exact).
template <int EPI>
__global__ __launch_bounds__(256) void gemm64_kernel(
    const ushort* __restrict__ A, const ushort* __restrict__ BT0,
    const ushort* __restrict__ BT1, int rowSplit, const float* __restrict__ b0,
    const float* __restrict__ b1, float sc1, void* __restrict__ Cout, int M,
    int N, int K) {
  __shared__ ushort As[64 * 32];
  __shared__ ushort Bs[128 * 32];
  const int m0 = blockIdx.x * 64, n0 = blockIdx.y * 128;
  const ushort* BT = (m0 < rowSplit) ? BT0 : BT1;
  const float* bias = (m0 < rowSplit) ? b0 : b1;
  const float sc = (m0 < rowSplit) ? 1.0f : sc1;
  const int tid = threadIdx.x;
  const int w = tid >> 6, lane = tid & 63, m15 = lane & 15, q4 = lane >> 4;
  float4v acc[4][2] = {};
  const int ra = tid >> 2, ua = (tid & 3) * 8;
  const int c0 = tid, c1 = tid + 256;
  const int rb0 = c0 >> 2, ub0 = (c0 & 3) * 8;
  const int rb1 = c1 >> 2, ub1 = (c1 & 3) * 8;

  for (int kk = 0; kk < K; kk += 32) {
    __syncthreads();
    gld16(&A[(m0 + ra) * K + kk + ua], &As[tid * 8]);
    gld16(&BT[(n0 + rb0) * K + kk + ub0], &Bs[c0 * 8]);
    gld16(&BT[(n0 + rb1) * K + kk + ub1], &Bs[c1 * 8]);
    __syncthreads();
    short8 bf[2];
#pragma unroll
    for (int j = 0; j < 2; ++j)
      bf[j] = *(const short8*)(&Bs[(w * 32 + j * 16 + m15) * 32 + q4 * 8]);
#pragma unroll
    for (int i = 0; i < 4; ++i) {
      short8 af = *(const short8*)(&As[(i * 16 + m15) * 32 + q4 * 8]);
#pragma unroll
      for (int j = 0; j < 2; ++j)
        acc[i][j] =
            __builtin_amdgcn_mfma_f32_16x16x32_bf16(af, bf[j], acc[i][j], 0, 0, 0);
    }
  }
#pragma unroll
  for (int j = 0; j < 2; ++j) {
    int col = n0 + w * 32 + j * 16 + m15;
    float bv = bias[col];
#pragma unroll
    for (int i = 0; i < 4; ++i) {
      int rowb = m0 + i * 16 + q4 * 4;
#pragma unroll
      for (int r = 0; r < 4; ++r) {
        float v = (acc[i][j][r] + bv) * sc;
        if (EPI == 1)
          ((float*)Cout)[(rowb + r) * N + col] = v;
        else
          ((ushort*)Cout)[(rowb + r) * N + col] = f2b(v);
      }
    }
  }
}

// ---------- fused attention: QK + on-the-fly B-hat bands + exp + PV ---------
// Wave-independent: wave = (st s-tile 16 rows, th T-half). Chunks of 32 t.
// B-hat is NOT materialized: per chunk, the 47 needed u-values form <=2
// diagonal bands; each band = 3 MFMAs vs Qrel (L2-hot), staged in wave-
// private LDS, gathered per-cell. Band A: u=t-s+1023 (<=2047) with q rows
// s0..s0+15. Band B: u>=2049 -> Bhat[s+1][u-2049], same gather offset, q
// rows shifted by one (afs). u==2048 -> 0. Qrel pre-scaled by 1/8.
__global__ __launch_bounds__(256) void attn_kernel(
    const ushort* __restrict__ qb, const ushort* __restrict__ kv,
    const ushort* __restrict__ vt, const ushort* __restrict__ Qrb,
    const ushort* __restrict__ maskb, ushort* __restrict__ attn) {
  __shared__ float Bt[4][2][16 * 50];   // [wave][band A/B][row][48+pad]
  __shared__ ushort Pp[4][16 * 36];
  __shared__ float comb[2][16][68];
  __shared__ float csum[32];

  const int tid = threadIdx.x;
  const int w = tid >> 6, lane = tid & 63, m15 = lane & 15, q4 = lane >> 4;
  const int st = w & 1, th = w >> 1;
  const int s0w = blockIdx.x * 32 + st * 16;
  const int h = blockIdx.y, b = blockIdx.z;
  const int s_l = q4 * 4;

  const ushort* qp = &qb[((b << 10) + s0w + m15) * 1024 + (h << 6) + q4 * 8];
  const short8 af0 = *(const short8*)qp;
  const short8 af1 = *(const short8*)(qp + 32);
  const int srow1 = (s0w + m15 + 1 > 1023) ? 1023 : (s0w + m15 + 1);
  const ushort* qps = &qb[((b << 10) + srow1) * 1024 + (h << 6) + q4 * 8];
  const short8 afs0 = *(const short8*)qps;
  const short8 afs1 = *(const short8*)(qps + 32);

  const ushort* kvb = &kv[((size_t)(b << 11) * 2048) + (h << 6)];
  const ushort* vtb = &vt[((size_t)((b << 10) + (h << 6))) * 2048];
  ushort* pw = &Pp[w][0];
  float* btA = &Bt[w][0][0];
  float* btB = &Bt[w][1][0];

  float lsum4[4] = {0.f, 0.f, 0.f, 0.f};
  float4v oacc[4] = {};

  short8 K0[2][2], K1[2][2];
  short8 QW0[3][2], QW1[3][2];
  ushort mk0[8], mk1[8];

  auto loadK = [&](int t0, short8 (&K)[2][2]) {
#pragma unroll
    for (int nt = 0; nt < 2; ++nt) {
      const ushort* kp = &kvb[(size_t)(t0 + nt * 16 + m15) * 2048 + q4 * 8];
      K[nt][0] = *(const short8*)kp;
      K[nt][1] = *(const short8*)(kp + 32);
    }
  };
  auto loadQW = [&](int t0, short8 (&QW)[3][2]) {
    const bool pA = (t0 <= s0w + 1039);
    const int wb = t0 - s0w + (pA ? 1008 : -1041);
#pragma unroll
    for (int tt = 0; tt < 3; ++tt) {
      int wr = wb + tt * 16 + m15;
      wr = wr < 0 ? 0 : (wr > 2047 ? 2047 : wr);
      const ushort* qrp = &Qrb[(size_t)wr * 1024 + (h << 6) + q4 * 8];
      QW[tt][0] = *(const short8*)qrp;
      QW[tt][1] = *(const short8*)(qrp + 32);
    }
  };
  auto loadMk = [&](int t0, ushort (&mk)[8]) {
#pragma unroll
    for (int nt = 0; nt < 2; ++nt)
#pragma unroll
      for (int i = 0; i < 4; ++i)
        mk[nt * 4 + i] = maskb[(s0w + s_l + i) * 2048 + t0 + nt * 16 + m15];
  };

  auto process = [&](int t0, short8 (&K)[2][2], short8 (&QW)[3][2],
                     ushort (&mk)[8], int pt0, short8 (&Kp)[2][2],
                     short8 (&QWp)[3][2], ushort (&mkp)[8], bool doPre) {
    // V loads issued first (oldest in VMEM queue -> PV wait keeps prefetch
    // in flight)
    short8 Vr[4];
#pragma unroll
    for (int nd = 0; nd < 4; ++nd)
      Vr[nd] = *(const short8*)(&vtb[(size_t)(nd * 16 + m15) * 2048 + t0 + q4 * 8]);
    // QK
    float4v a0 = {}, a1 = {};
    a0 = __builtin_amdgcn_mfma_f32_16x16x32_bf16(af0, K[0][0], a0, 0, 0, 0);
    a0 = __builtin_amdgcn_mfma_f32_16x16x32_bf16(af1, K[0][1], a0, 0, 0, 0);
    a1 = __builtin_amdgcn_mfma_f32_16x16x32_bf16(af0, K[1][0], a1, 0, 0, 0);
    a1 = __builtin_amdgcn_mfma_f32_16x16x32_bf16(af1, K[1][1], a1, 0, 0, 0);
    // prefetch next chunk
    if (doPre) {
      loadK(pt0, Kp);
      loadQW(pt0, QWp);
      loadMk(pt0, mkp);
    }
    // primary B-hat band (A if available, else B); wave-uniform branch
    const bool pA = (t0 <= s0w + 1039);
    const bool nB = (t0 >= s0w + 995);
    const short8 pa0 = pA ? af0 : afs0;
    const short8 pa1 = pA ? af1 : afs1;
    float4v bh0 = {}, bh1 = {}, bh2 = {};
    bh0 = __builtin_amdgcn_mfma_f32_16x16x32_bf16(pa0, QW[0][0], bh0, 0, 0, 0);
    bh0 = __builtin_amdgcn_mfma_f32_16x16x32_bf16(pa1, QW[0][1], bh0, 0, 0, 0);
    bh1 = __builtin_amdgcn_mfma_f32_16x16x32_bf16(pa0, QW[1][0], bh1, 0, 0, 0);
    bh1 = __builtin_amdgcn_mfma_f32_16x16x32_bf16(pa1, QW[1][1], bh1, 0, 0, 0);
    bh2 = __builtin_amdgcn_mfma_f32_16x16x32_bf16(pa0, QW[2][0], bh2, 0, 0, 0);
    bh2 = __builtin_amdgcn_mfma_f32_16x16x32_bf16(pa1, QW[2][1], bh2, 0, 0, 0);
    float* btP = pA ? btA : btB;
#pragma unroll
    for (int i = 0; i < 4; ++i) {
      btP[(s_l + i) * 50 + m15] = bh0[i];
      btP[(s_l + i) * 50 + 16 + m15] = bh1[i];
      btP[(s_l + i) * 50 + 32 + m15] = bh2[i];
    }
    if (pA && nB) {   // straddle chunk (1-2 per wave): also band B
      const int vb = t0 - s0w - 1041;
      float4v bs0 = {}, bs1 = {}, bs2 = {};
#pragma unroll
      for (int tt = 0; tt < 3; ++tt) {
        int wr = vb + tt * 16 + m15;
        wr = wr < 0 ? 0 : wr;
        const ushort* qrp = &Qrb[(size_t)wr * 1024 + (h << 6) + q4 * 8];
        short8 qs0 = *(const short8*)qrp;
        short8 qs1 = *(const short8*)(qrp + 32);
        if (tt == 0) {
          bs0 = __builtin_amdgcn_mfma_f32_16x16x32_bf16(afs0, qs0, bs0, 0, 0, 0);
          bs0 = __builtin_amdgcn_mfma_f32_16x16x32_bf16(afs1, qs1, bs0, 0, 0, 0);
        } else if (tt == 1) {
          bs1 = __builtin_amdgcn_mfma_f32_16x16x32_bf16(afs0, qs0, bs1, 0, 0, 0);
          bs1 = __builtin_amdgcn_mfma_f32_16x16x32_bf16(afs1, qs1, bs1, 0, 0, 0);
        } else {
          bs2 = __builtin_amdgcn_mfma_f32_16x16x32_bf16(afs0, qs0, bs2, 0, 0, 0);
          bs2 = __builtin_amdgcn_mfma_f32_16x16x32_bf16(afs1, qs1, bs2, 0, 0, 0);
        }
      }
#pragma unroll
      for (int i = 0; i < 4; ++i) {
        btB[(s_l + i) * 50 + m15] = bs0[i];
        btB[(s_l + i) * 50 + 16 + m15] = bs1[i];
        btB[(s_l + i) * 50 + 32 + m15] = bs2[i];
      }
    }
    // gather + exp -> Pp (wave-private LDS, in-order within wave)
#pragma unroll
    for (int nt = 0; nt < 2; ++nt) {
#pragma unroll
      for (int i = 0; i < 4; ++i) {
        int s = s0w + s_l + i;
        int t = t0 + nt * 16 + m15;
        int u = t - s + 1023;
        int off = (s_l + i) * 50 + (nt * 16 + m15) - (s_l + i) + 15;
        const float* bp = (u <= 2047) ? btA : btB;
        float bval = bp[off];
        bval = (u == 2048) ? 0.f : bval;
        float a = (nt == 0) ? a0[i] : a1[i];
        float p = __expf(a + bval + b2f(mk[nt * 4 + i]));
        lsum4[i] += p;
        pw[(s_l + i) * 36 + nt * 16 + m15] = f2b(p);
      }
    }
    // PV
    short8 pfr = *(const short8*)(&pw[m15 * 36 + q4 * 8]);
#pragma unroll
    for (int nd = 0; nd < 4; ++nd)
      oacc[nd] =
          __builtin_amdgcn_mfma_f32_16x16x32_bf16(pfr, Vr[nd], oacc[nd], 0, 0, 0);
  };

  const int tb = th * 1024;
  loadK(tb, K0);
  loadQW(tb, QW0);
  loadMk(tb, mk0);
  for (int ci2 = 0; ci2 < 16; ++ci2) {
    const int t0 = tb + ci2 * 64;
    process(t0, K0, QW0, mk0, t0 + 32, K1, QW1, mk1, true);
    process(t0 + 32, K1, QW1, mk1, t0 + 64, K0, QW0, mk0, ci2 < 15);
  }

  // row sums across the 16 t-lanes (m15 butterfly)
#pragma unroll
  for (int i = 0; i < 4; ++i) {
    float v = lsum4[i];
    v += __shfl_xor(v, 1, 64);
    v += __shfl_xor(v, 2, 64);
    v += __shfl_xor(v, 4, 64);
    v += __shfl_xor(v, 8, 64);
    lsum4[i] = v;
  }
  // combine T-halves
  if (th == 1) {
#pragma unroll
    for (int nd = 0; nd < 4; ++nd)
#pragma unroll
      for (int i = 0; i < 4; ++i)
        comb[st][s_l + i][nd * 16 + m15] = oacc[nd][i];
    if (m15 == 0)
#pragma unroll
      for (int i = 0; i < 4; ++i) csum[st * 16 + s_l + i] = lsum4[i];
  }
  __syncthreads();
  if (th == 0) {
#pragma unroll
    for (int i = 0; i < 4; ++i) lsum4[i] += csum[st * 16 + s_l + i];
#pragma unroll
    for (int nd = 0; nd < 4; ++nd)
#pragma unroll
      for (int i = 0; i < 4; ++i) {
        float v = oacc[nd][i] + comb[st][s_l + i][nd * 16 + m15];
        attn[((b << 10) + s0w + s_l + i) * 1024 + (h << 6) + nd * 16 + m15] =
            f2b(v / lsum4[i]);
      }
  }
}

// ---------------------------------------------------------------- launch ----
extern "C" void kernel_launch(void* const* d_in, const int* in_sizes, int n_in,
                              void* d_out, int out_size, void* d_ws,
                              size_t ws_size, hipStream_t stream) {
  const float* x = (const float*)d_in[0];
  const float* mem = (const float*)d_in[1];
  const float* mask = (const float*)d_in[2];
  const float* rel = (const float*)d_in[3];
  const float* Wq = (const float*)d_in[4];
  const float* bq = (const float*)d_in[5];
  const float* Wke = (const float*)d_in[6];
  const float* bke = (const float*)d_in[7];
  const float* Wkr = (const float*)d_in[8];
  const float* bkr = (const float*)d_in[9];
  const float* Wv = (const float*)d_in[10];
  const float* bv = (const float*)d_in[11];
  const float* Wo = (const float*)d_in[12];
  const float* bo = (const float*)d_in[13];
  float* out = (float*)d_out;

  ushort* ws = (ushort*)d_ws;
  ushort* xt = ws;                          // 4096x1024 (reused as vt)
  ushort* xbrel = xt + 4096 * 1024;         // [xb(2048); relb(2048)] x 1024
  ushort* WqT = xbrel + 4096 * 1024;
  ushort* WkeT = WqT + 1024 * 1024;
  ushort* WvT = WkeT + 1024 * 1024;
  ushort* WkrT = WvT + 1024 * 1024;
  ushort* WoT = WkrT + 1024 * 1024;
  ushort* kv = WoT + 1024 * 1024;           // 4096x2048 (K cols scaled, V)
  ushort* qr = kv + 4096 * 2048;            // [qbuf(2048); Qrb(2048)] x 1024
  ushort* attn = qr + 4096 * 1024;          // 2048x1024
  ushort* maskb = attn + 2048 * 1024;       // 1024x2048 bf16 pre-scaled
  ushort* relb = xbrel + 2048 * 1024;
  ushort* Qrb = qr + 2048 * 1024;           // Qrel, pre-scaled by 1/8
  ushort* vt = xt;

  concat_cvt_kernel<<<2048, 256, 0, stream>>>(x, mem, xt, xbrel);
  cvt_kernel<<<1024, 256, 0, stream>>>(rel, relb);
  maskcvt_kernel<<<1024, 256, 0, stream>>>(mask, maskb);
  transpose_cvt5_kernel<<<dim3(32, 32, 5), 256, 0, stream>>>(
      Wq, Wke, Wkr, Wv, Wo, WqT, WkeT, WkrT, WvT, WoT);

  gemm128_kernel<<<dim3(32, 16), 256, 0, stream>>>(xt, WkeT, bke, bv, kv,
                                                   4096, 2048, 1024);
  gemm64_kernel<0><<<dim3(64, 8), 256, 0, stream>>>(
      xbrel, WqT, WkrT, 2048, bq, bkr, 0.125f, qr, 4096, 1024, 1024);
  vtrans_kernel<<<dim3(128, 16), 256, 0, stream>>>(kv, vt);

  attn_kernel<<<dim3(SEQ / 32, NH, BATCH), 256, 0, stream>>>(
      qr, kv, vt, Qrb, maskb, attn);

  gemm64_kernel<1><<<dim3(32, 8), 256, 0, stream>>>(
      attn, WoT, WoT, 1 << 30, bo, bo, 1.0f, out, 2048, 1024, 1024);
}

// Round 4
// 371.559 us; speedup vs baseline: 1.0949x; 1.0780x over previous
//
#include <hip/hip_runtime.h>

typedef unsigned short ushort;
typedef unsigned int uint;
typedef __attribute__((ext_vector_type(8))) short short8;
typedef __attribute__((ext_vector_type(4))) float float4v;

#define D_MODEL 1024
#define NH 16
#define DH 64
#define BATCH 2
#define SEQ 1024
#define MEMLEN 1024
#define TOT 2048

__device__ __forceinline__ float b2f(ushort u) {
  return __uint_as_float(((uint)u) << 16);
}
__device__ __forceinline__ ushort f2b(float f) {
  uint i = __float_as_uint(f);
  uint r = (i + 0x7fffu + ((i >> 16) & 1u)) >> 16;
  return (ushort)r;
}
__device__ __forceinline__ void gld16(const ushort* g, ushort* l) {
  __builtin_amdgcn_global_load_lds(
      (const __attribute__((address_space(1))) void*)g,
      (__attribute__((address_space(3))) void*)l, 16, 0, 0);
}

// ------------------------------------------------- concat + cast to bf16 ----
__global__ __launch_bounds__(256) void concat_cvt_kernel(
    const float* __restrict__ x, const float* __restrict__ mem,
    ushort* __restrict__ xt, ushort* __restrict__ xb) {
  int idx = blockIdx.x * 256 + threadIdx.x;
  int row = idx >> 7;
  int c8 = (idx & 127) << 3;
  int b = row >> 11;
  int i = row & 2047;
  const float* src = (i < MEMLEN) ? &mem[((b << 10) + i) * D_MODEL]
                                  : &x[((b << 10) + (i - MEMLEN)) * D_MODEL];
  float4 f0 = *(const float4*)(&src[c8]);
  float4 f1 = *(const float4*)(&src[c8 + 4]);
  ushort u[8] = {f2b(f0.x), f2b(f0.y), f2b(f0.z), f2b(f0.w),
                 f2b(f1.x), f2b(f1.y), f2b(f1.z), f2b(f1.w)};
  *(uint4*)(&xt[row * D_MODEL + c8]) = *(const uint4*)u;
  if (i >= MEMLEN)
    *(uint4*)(&xb[((b << 10) + (i - MEMLEN)) * D_MODEL + c8]) = *(const uint4*)u;
}

// --------------------------------------------------- fp32 -> bf16 cast ------
__global__ __launch_bounds__(256) void cvt_kernel(const float* __restrict__ in,
                                                  ushort* __restrict__ out) {
  int idx = blockIdx.x * 256 + threadIdx.x;
  int base = idx << 3;
  float4 f0 = *(const float4*)(&in[base]);
  float4 f1 = *(const float4*)(&in[base + 4]);
  ushort u[8] = {f2b(f0.x), f2b(f0.y), f2b(f0.z), f2b(f0.w),
                 f2b(f1.x), f2b(f1.y), f2b(f1.z), f2b(f1.w)};
  *(uint4*)(&out[base]) = *(const uint4*)u;
}

// --------------------- mask -> bf16 pre-multiplied by -1e9 ------------------
__global__ __launch_bounds__(256) void maskcvt_kernel(
    const float* __restrict__ in, ushort* __restrict__ out) {
  int idx = blockIdx.x * 256 + threadIdx.x;
  int base = idx << 3;
  float4 f0 = *(const float4*)(&in[base]);
  float4 f1 = *(const float4*)(&in[base + 4]);
  ushort u[8] = {f2b(f0.x * -1e9f), f2b(f0.y * -1e9f), f2b(f0.z * -1e9f),
                 f2b(f0.w * -1e9f), f2b(f1.x * -1e9f), f2b(f1.y * -1e9f),
                 f2b(f1.z * -1e9f), f2b(f1.w * -1e9f)};
  *(uint4*)(&out[base]) = *(const uint4*)u;
}

// --------------------------- 5x transpose + cast to bf16 (one launch) -------
__global__ __launch_bounds__(256) void transpose_cvt5_kernel(
    const float* __restrict__ W0, const float* __restrict__ W1,
    const float* __restrict__ W2, const float* __restrict__ W3,
    const float* __restrict__ W4, ushort* __restrict__ T0,
    ushort* __restrict__ T1, ushort* __restrict__ T2, ushort* __restrict__ T3,
    ushort* __restrict__ T4) {
  __shared__ ushort tle[32][33];
  const float* W;
  ushort* T;
  switch (blockIdx.z) {
    case 0: W = W0; T = T0; break;
    case 1: W = W1; T = T1; break;
    case 2: W = W2; T = T2; break;
    case 3: W = W3; T = T3; break;
    default: W = W4; T = T4; break;
  }
  const int bx = blockIdx.x * 32, by = blockIdx.y * 32;
  const int tx = threadIdx.x & 31, ty = threadIdx.x >> 5;
#pragma unroll
  for (int j = 0; j < 32; j += 8)
    tle[ty + j][tx] = f2b(W[(by + ty + j) * 1024 + bx + tx]);
  __syncthreads();
#pragma unroll
  for (int j = 0; j < 32; j += 8)
    T[(bx + ty + j) * 1024 + by + tx] = tle[tx][ty + j];
}

// ------------------------------------- V transpose: kv cols -> vt[b][d][t] --
__global__ __launch_bounds__(256) void vtrans_kernel(
    const ushort* __restrict__ kv, ushort* __restrict__ vt) {
  __shared__ ushort tle[32][76];
  const int gx = blockIdx.x;   // 32-row (b,t) tiles
  const int gy = blockIdx.y;   // 64-wide d tiles
  const int tid = threadIdx.x;
  const int r = tid >> 3, c8 = (tid & 7) * 8;
  *(uint4*)(&tle[r][c8]) =
      *(const uint4*)(&kv[(gx * 32 + r) * 2048 + 1024 + gy * 64 + c8]);
  __syncthreads();
  const int dr = tid >> 2, tc8 = (tid & 3) * 8;
  const int bb = (gx * 32) >> 11, tbase = (gx * 32) & 2047;
  ushort tmp[8];
#pragma unroll
  for (int j = 0; j < 8; ++j) tmp[j] = tle[tc8 + j][dr];
  *(uint4*)(&vt[((bb << 10) + gy * 64 + dr) * 2048 + tbase + tc8]) =
      *(const uint4*)tmp;
}

// -------------------------------------------------- 128x128 m97-style GEMM --
// KV projection: cols<1024 = K (scaled 0.125 with bke), cols>=1024 = V (bv).
__global__ __launch_bounds__(256) void gemm128_kernel(
    const ushort* __restrict__ A, const ushort* __restrict__ BT,
    const float* __restrict__ b0, const float* __restrict__ b1,
    ushort* __restrict__ Cout, int M, int N, int K) {
  __shared__ ushort As[128 * 32];
  __shared__ ushort Bs[128 * 32];
  const int m0 = blockIdx.x * 128, n0 = blockIdx.y * 128;
  const int tid = threadIdx.x;
  const int w = tid >> 6, lane = tid & 63, m15 = lane & 15, q4 = lane >> 4;
  const int wm = w & 1, wn = w >> 1;
  float4v acc[4][4] = {};
  const int c0 = tid, c1 = tid + 256;
  const int r0 = c0 >> 2, u0 = (c0 & 3) * 8;
  const int r1 = c1 >> 2, u1 = (c1 & 3) * 8;

  for (int kk = 0; kk < K; kk += 32) {
    __syncthreads();
    gld16(&A[(m0 + r0) * K + kk + u0], &As[c0 * 8]);
    gld16(&A[(m0 + r1) * K + kk + u1], &As[c1 * 8]);
    gld16(&BT[(n0 + r0) * K + kk + u0], &Bs[c0 * 8]);
    gld16(&BT[(n0 + r1) * K + kk + u1], &Bs[c1 * 8]);
    __syncthreads();
    short8 af[4], bf[4];
#pragma unroll
    for (int i = 0; i < 4; ++i)
      af[i] = *(const short8*)(&As[(wm * 64 + i * 16 + m15) * 32 + q4 * 8]);
#pragma unroll
    for (int j = 0; j < 4; ++j)
      bf[j] = *(const short8*)(&Bs[(wn * 64 + j * 16 + m15) * 32 + q4 * 8]);
#pragma unroll
    for (int i = 0; i < 4; ++i)
#pragma unroll
      for (int j = 0; j < 4; ++j)
        acc[i][j] =
            __builtin_amdgcn_mfma_f32_16x16x32_bf16(af[i], bf[j], acc[i][j], 0, 0, 0);
  }
#pragma unroll
  for (int j = 0; j < 4; ++j) {
    int col = n0 + wn * 64 + j * 16 + m15;
    float bv = (col < 1024) ? b0[col] : b1[col - 1024];
    float sc = (col < 1024) ? 0.125f : 1.0f;   // pre-scale K by 1/8 (exact)
#pragma unroll
    for (int i = 0; i < 4; ++i) {
      int rowb = m0 + wm * 64 + i * 16 + q4 * 4;
#pragma unroll
      for (int r = 0; r < 4; ++r)
        Cout[(rowb + r) * N + col] = f2b((acc[i][j][r] + bv) * sc);
    }
  }
}

// -------------------------------------- 64x128-tile GEMM (for small M) ------
// sc1 is applied to rows >= rowSplit (used to pre-scale Qrel by 1/8, exact).
template <int EPI>
__global__ __launch_bounds__(256) void gemm64_kernel(
    const ushort* __restrict__ A, const ushort* __restrict__ BT0,
    const ushort* __restrict__ BT1, int rowSplit, const float* __restrict__ b0,
    const float* __restrict__ b1, float sc1, void* __restrict__ Cout, int M,
    int N, int K) {
  __shared__ ushort As[64 * 32];
  __shared__ ushort Bs[128 * 32];
  const int m0 = blockIdx.x * 64, n0 = blockIdx.y * 128;
  const ushort* BT = (m0 < rowSplit) ? BT0 : BT1;
  const float* bias = (m0 < rowSplit) ? b0 : b1;
  const float sc = (m0 < rowSplit) ? 1.0f : sc1;
  const int tid = threadIdx.x;
  const int w = tid >> 6, lane = tid & 63, m15 = lane & 15, q4 = lane >> 4;
  float4v acc[4][2] = {};
  const int ra = tid >> 2, ua = (tid & 3) * 8;
  const int c0 = tid, c1 = tid + 256;
  const int rb0 = c0 >> 2, ub0 = (c0 & 3) * 8;
  const int rb1 = c1 >> 2, ub1 = (c1 & 3) * 8;

  for (int kk = 0; kk < K; kk += 32) {
    __syncthreads();
    gld16(&A[(m0 + ra) * K + kk + ua], &As[tid * 8]);
    gld16(&BT[(n0 + rb0) * K + kk + ub0], &Bs[c0 * 8]);
    gld16(&BT[(n0 + rb1) * K + kk + ub1], &Bs[c1 * 8]);
    __syncthreads();
    short8 bf[2];
#pragma unroll
    for (int j = 0; j < 2; ++j)
      bf[j] = *(const short8*)(&Bs[(w * 32 + j * 16 + m15) * 32 + q4 * 8]);
#pragma unroll
    for (int i = 0; i < 4; ++i) {
      short8 af = *(const short8*)(&As[(i * 16 + m15) * 32 + q4 * 8]);
#pragma unroll
      for (int j = 0; j < 2; ++j)
        acc[i][j] =
            __builtin_amdgcn_mfma_f32_16x16x32_bf16(af, bf[j], acc[i][j], 0, 0, 0);
    }
  }
#pragma unroll
  for (int j = 0; j < 2; ++j) {
    int col = n0 + w * 32 + j * 16 + m15;
    float bv = bias[col];
#pragma unroll
    for (int i = 0; i < 4; ++i) {
      int rowb = m0 + i * 16 + q4 * 4;
#pragma unroll
      for (int r = 0; r < 4; ++r) {
        float v = (acc[i][j][r] + bv) * sc;
        if (EPI == 1)
          ((float*)Cout)[(rowb + r) * N + col] = v;
        else
          ((ushort*)Cout)[(rowb + r) * N + col] = f2b(v);
      }
    }
  }
}

// ----------------------- Bhat batched GEMM + mask fold ----------------------
// Bh[b,h,sp,u] = q[sp].Qrel[u] (Qrel pre-scaled 1/8) + mask for the (s,t)
// cell that will READ this element in attn. Band-A reads (u >= 1023-sp,
// consumer (sp, t=u+sp-1023)) and wrap reads (u < 1023-sp, consumer
// (sp-1, t=u+sp+1025)) are provably disjoint, so exactly one mask value is
// correct per cell. Mask reads are row-contiguous (L2-hot, 4 MB).
__global__ __launch_bounds__(256) void bhat_kernel(
    const ushort* __restrict__ q, const ushort* __restrict__ Qrb,
    const ushort* __restrict__ maskb, ushort* __restrict__ Bh) {
  __shared__ ushort As[2 * 128 * 32];
  __shared__ ushort Bs[2 * 128 * 32];
  const int bs0 = blockIdx.x * 128, u0 = blockIdx.y * 128, h = blockIdx.z;
  const int tid = threadIdx.x;
  const int w = tid >> 6, lane = tid & 63, m15 = lane & 15, q4 = lane >> 4;
  const int wm = w & 1, wn = w >> 1;

#pragma unroll
  for (int c = 0; c < 4; ++c) {
    int unit = c * 256 + tid;               // flat LDS ushort = unit*8
    int row = (unit >> 2) & 127, kh = unit >> 9, cu = unit & 3;
    gld16(&q[(bs0 + row) * 1024 + (h << 6) + kh * 32 + cu * 8], &As[unit * 8]);
    gld16(&Qrb[(u0 + row) * 1024 + (h << 6) + kh * 32 + cu * 8], &Bs[unit * 8]);
  }
  __syncthreads();

  float4v acc[4][4] = {};
#pragma unroll
  for (int kh = 0; kh < 2; ++kh) {
    short8 af[4], bf[4];
#pragma unroll
    for (int i = 0; i < 4; ++i)
      af[i] = *(const short8*)(&As[kh * 4096 + (wm * 64 + i * 16 + m15) * 32 + q4 * 8]);
#pragma unroll
    for (int j = 0; j < 4; ++j)
      bf[j] = *(const short8*)(&Bs[kh * 4096 + (wn * 64 + j * 16 + m15) * 32 + q4 * 8]);
#pragma unroll
    for (int i = 0; i < 4; ++i)
#pragma unroll
      for (int j = 0; j < 4; ++j)
        acc[i][j] =
            __builtin_amdgcn_mfma_f32_16x16x32_bf16(af[i], bf[j], acc[i][j], 0, 0, 0);
  }
  const int b = bs0 >> 10;
  const int s0loc = bs0 & 1023;
  const int outrow0 = ((b << 4) + h) * 1024 + s0loc;
#pragma unroll
  for (int j = 0; j < 4; ++j) {
    int u = u0 + wn * 64 + j * 16 + m15;
#pragma unroll
    for (int i = 0; i < 4; ++i) {
      int rowb = outrow0 + wm * 64 + i * 16 + q4 * 4;
      int spb = s0loc + wm * 64 + i * 16 + q4 * 4;
#pragma unroll
      for (int r = 0; r < 4; ++r) {
        int sp = spb + r;
        bool selA = (u >= 1023 - sp);
        int mrow = selA ? sp : (sp > 0 ? sp - 1 : 0);
        int mcol = selA ? (u + sp - 1023) : (u + sp + 1025);
        float mval = b2f(maskb[mrow * 2048 + mcol]);
        Bh[(rowb + r) * 2048 + u] = f2b(acc[i][j][r] + mval);
      }
    }
  }
}

// ----------------- fused attention: QK + deep B-gather + exp + PV -----------
// Wave-independent: wave = (st s-tile 16 rows, th T-half). Chunks of 32 t.
// ZERO barriers in the loop. B-hat gather (the only HBM-latency stream) is
// prefetched FOUR chunks ahead via 4 rotating static register buffers
// (~1400 cy cover > ~900 cy HBM latency). Mask is pre-folded into Bh by the
// producer; the u==2048 zero-diagonal's mask is preloaded per wave (dm).
// Gather address: band A (t <= s+1024): Bh[s][t-s+1023]; else wrap:
// Bh[s+1][t-s-1026]; both via precomputed per-row base offsets.
__global__ __launch_bounds__(256) void attn_kernel(
    const ushort* __restrict__ qb, const ushort* __restrict__ kv,
    const ushort* __restrict__ vt, const ushort* __restrict__ Bh,
    const ushort* __restrict__ maskb, ushort* __restrict__ attn) {
  __shared__ ushort Pp[4][16 * 36];
  __shared__ float comb[2][16][68];
  __shared__ float csum[32];

  const int tid = threadIdx.x;
  const int w = tid >> 6, lane = tid & 63, m15 = lane & 15, q4 = lane >> 4;
  const int st = w & 1, th = w >> 1;
  const int s0w = blockIdx.x * 32 + st * 16;
  const int h = blockIdx.y, b = blockIdx.z;
  const int s_l = q4 * 4;

  const ushort* qp = &qb[((b << 10) + s0w + m15) * 1024 + (h << 6) + q4 * 8];
  const short8 af0 = *(const short8*)qp;
  const short8 af1 = *(const short8*)(qp + 32);

  const ushort* kvb = &kv[((size_t)(b << 11) * 2048) + (h << 6)];
  const ushort* vtb = &vt[((size_t)((b << 10) + (h << 6))) * 2048];
  const int bhbase = ((b << 4) + h) << 21;   // *(1024*2048)
  ushort* pw = &Pp[w][0];

  int offA[4], offB[4], diagT[4];
  float dm[4];
#pragma unroll
  for (int i = 0; i < 4; ++i) {
    int s = s0w + s_l + i;
    offA[i] = bhbase + (s << 11) - s + 1023;
    offB[i] = bhbase + ((s + 1) << 11) - s - 1026;
    diagT[i] = s + 1025;
    dm[i] = (diagT[i] <= 2047) ? b2f(maskb[s * 2048 + diagT[i]]) : 0.f;
  }

  float lsum4[4] = {0.f, 0.f, 0.f, 0.f};
  float4v oacc[4] = {};
  ushort Bb0[8], Bb1[8], Bb2[8], Bb3[8];

  auto pre_bh = [&](int t0, ushort (&B)[8]) {
#pragma unroll
    for (int nt = 0; nt < 2; ++nt)
#pragma unroll
      for (int i = 0; i < 4; ++i) {
        int t = t0 + nt * 16 + m15;
        int off = (t < diagT[i]) ? offA[i] : offB[i];   // t <= s+1024 -> A
        B[nt * 4 + i] = Bh[off + t];
      }
  };

  auto phase = [&](int t0, ushort (&Bb)[8], bool pf) {
    short8 Vr[4], Kr[2][2];
#pragma unroll
    for (int nd = 0; nd < 4; ++nd)
      Vr[nd] = *(const short8*)(&vtb[(size_t)(nd * 16 + m15) * 2048 + t0 + q4 * 8]);
#pragma unroll
    for (int nt = 0; nt < 2; ++nt) {
      const ushort* kp = &kvb[(size_t)(t0 + nt * 16 + m15) * 2048 + q4 * 8];
      Kr[nt][0] = *(const short8*)kp;
      Kr[nt][1] = *(const short8*)(kp + 32);
    }
    ushort cur[8];
#pragma unroll
    for (int j = 0; j < 8; ++j) cur[j] = Bb[j];
    if (pf) pre_bh(t0 + 128, Bb);
    float4v a0 = {}, a1 = {};
    a0 = __builtin_amdgcn_mfma_f32_16x16x32_bf16(af0, Kr[0][0], a0, 0, 0, 0);
    a0 = __builtin_amdgcn_mfma_f32_16x16x32_bf16(af1, Kr[0][1], a0, 0, 0, 0);
    a1 = __builtin_amdgcn_mfma_f32_16x16x32_bf16(af0, Kr[1][0], a1, 0, 0, 0);
    a1 = __builtin_amdgcn_mfma_f32_16x16x32_bf16(af1, Kr[1][1], a1, 0, 0, 0);
#pragma unroll
    for (int nt = 0; nt < 2; ++nt)
#pragma unroll
      for (int i = 0; i < 4; ++i) {
        int t = t0 + nt * 16 + m15;
        float bv = (t == diagT[i]) ? dm[i] : b2f(cur[nt * 4 + i]);
        float a = (nt == 0) ? a0[i] : a1[i];
        float p = __expf(a + bv);
        lsum4[i] += p;
        pw[(s_l + i) * 36 + nt * 16 + m15] = f2b(p);
      }
    short8 pfr = *(const short8*)(&pw[m15 * 36 + q4 * 8]);
#pragma unroll
    for (int nd = 0; nd < 4; ++nd)
      oacc[nd] =
          __builtin_amdgcn_mfma_f32_16x16x32_bf16(pfr, Vr[nd], oacc[nd], 0, 0, 0);
  };

  const int tb = th * 1024;
  pre_bh(tb, Bb0);
  pre_bh(tb + 32, Bb1);
  pre_bh(tb + 64, Bb2);
  pre_bh(tb + 96, Bb3);
  for (int it = 0; it < 8; ++it) {
    const int t0 = tb + it * 128;
    const bool pf = (it < 7);
    phase(t0, Bb0, pf);
    phase(t0 + 32, Bb1, pf);
    phase(t0 + 64, Bb2, pf);
    phase(t0 + 96, Bb3, pf);
  }

  // row sums across the 16 t-lanes (m15 butterfly)
#pragma unroll
  for (int i = 0; i < 4; ++i) {
    float v = lsum4[i];
    v += __shfl_xor(v, 1, 64);
    v += __shfl_xor(v, 2, 64);
    v += __shfl_xor(v, 4, 64);
    v += __shfl_xor(v, 8, 64);
    lsum4[i] = v;
  }
  // combine T-halves
  if (th == 1) {
#pragma unroll
    for (int nd = 0; nd < 4; ++nd)
#pragma unroll
      for (int i = 0; i < 4; ++i)
        comb[st][s_l + i][nd * 16 + m15] = oacc[nd][i];
    if (m15 == 0)
#pragma unroll
      for (int i = 0; i < 4; ++i) csum[st * 16 + s_l + i] = lsum4[i];
  }
  __syncthreads();
  if (th == 0) {
#pragma unroll
    for (int i = 0; i < 4; ++i) lsum4[i] += csum[st * 16 + s_l + i];
#pragma unroll
    for (int nd = 0; nd < 4; ++nd)
#pragma unroll
      for (int i = 0; i < 4; ++i) {
        float v = oacc[nd][i] + comb[st][s_l + i][nd * 16 + m15];
        attn[((b << 10) + s0w + s_l + i) * 1024 + (h << 6) + nd * 16 + m15] =
            f2b(v / lsum4[i]);
      }
  }
}

// ---------------------------------------------------------------- launch ----
extern "C" void kernel_launch(void* const* d_in, const int* in_sizes, int n_in,
                              void* d_out, int out_size, void* d_ws,
                              size_t ws_size, hipStream_t stream) {
  const float* x = (const float*)d_in[0];
  const float* mem = (const float*)d_in[1];
  const float* mask = (const float*)d_in[2];
  const float* rel = (const float*)d_in[3];
  const float* Wq = (const float*)d_in[4];
  const float* bq = (const float*)d_in[5];
  const float* Wke = (const float*)d_in[6];
  const float* bke = (const float*)d_in[7];
  const float* Wkr = (const float*)d_in[8];
  const float* bkr = (const float*)d_in[9];
  const float* Wv = (const float*)d_in[10];
  const float* bv = (const float*)d_in[11];
  const float* Wo = (const float*)d_in[12];
  const float* bo = (const float*)d_in[13];
  float* out = (float*)d_out;

  ushort* ws = (ushort*)d_ws;
  ushort* xt = ws;                          // 4096x1024 (reused as vt)
  ushort* xbrel = xt + 4096 * 1024;         // [xb(2048); relb(2048)] x 1024
  ushort* WqT = xbrel + 4096 * 1024;
  ushort* WkeT = WqT + 1024 * 1024;
  ushort* WvT = WkeT + 1024 * 1024;
  ushort* WkrT = WvT + 1024 * 1024;
  ushort* WoT = WkrT + 1024 * 1024;
  ushort* kv = WoT + 1024 * 1024;           // 4096x2048 (K cols scaled, V)
  ushort* qr = kv + 4096 * 2048;            // [qbuf(2048); Qrb(2048)] x 1024
  ushort* attn = qr + 4096 * 1024;          // 2048x1024
  ushort* maskb = attn + 2048 * 1024;       // 1024x2048 bf16 pre-scaled
  ushort* Bh = maskb + 1024 * 2048;         // [b*16+h][1024 s][2048 u] bf16
  ushort* relb = xbrel + 2048 * 1024;
  ushort* Qrb = qr + 2048 * 1024;           // Qrel, pre-scaled by 1/8
  ushort* vt = xt;

  concat_cvt_kernel<<<2048, 256, 0, stream>>>(x, mem, xt, xbrel);
  cvt_kernel<<<1024, 256, 0, stream>>>(rel, relb);
  maskcvt_kernel<<<1024, 256, 0, stream>>>(mask, maskb);
  transpose_cvt5_kernel<<<dim3(32, 32, 5), 256, 0, stream>>>(
      Wq, Wke, Wkr, Wv, Wo, WqT, WkeT, WkrT, WvT, WoT);

  gemm128_kernel<<<dim3(32, 16), 256, 0, stream>>>(xt, WkeT, bke, bv, kv,
                                                   4096, 2048, 1024);
  gemm64_kernel<0><<<dim3(64, 8), 256, 0, stream>>>(
      xbrel, WqT, WkrT, 2048, bq, bkr, 0.125f, qr, 4096, 1024, 1024);
  vtrans_kernel<<<dim3(128, 16), 256, 0, stream>>>(kv, vt);

  bhat_kernel<<<dim3(16, 16, 16), 256, 0, stream>>>(qr, Qrb, maskb, Bh);

  attn_kernel<<<dim3(SEQ / 32, NH, BATCH), 256, 0, stream>>>(
      qr, kv, vt, Bh, maskb, attn);

  gemm64_kernel<1><<<dim3(32, 8), 256, 0, stream>>>(
      attn, WoT, WoT, 1 << 30, bo, bo, 1.0f, out, 2048, 1024, 1024);
}